// Round 6
// baseline (173.009 us; speedup 1.0000x reference)
//
#include <hip/hip_runtime.h>
#include <hip/hip_bf16.h>
#include <math.h>

#define NN 100000
#define FF 256
#define EE 128
#define BB_ 10000
#define DD 32

typedef __attribute__((ext_vector_type(8))) short short8;
typedef __attribute__((ext_vector_type(4))) float f32x4;

__device__ __forceinline__ short f2bf(float f) {
  __hip_bfloat16 h = __float2bfloat16(f);   // HW RNE cvt
  union { __hip_bfloat16 h; short s; } u; u.h = h;
  return u.s;
}
__device__ __forceinline__ float bf2f(short s) {
  union { unsigned u; float f; } v;
  v.u = ((unsigned)(unsigned short)s) << 16;
  return v.f;
}

// async global->LDS, 16B per lane; LDS dest = wave-uniform base + lane*16
__device__ __forceinline__ void gll16(const float* g, float* lds) {
  __builtin_amdgcn_global_load_lds(
      (const __attribute__((address_space(1))) unsigned int*)g,
      (__attribute__((address_space(3))) unsigned int*)lds, 16, 0, 0);
}

// ---- prep: Wef32 = W*z (fp32), BT2 X-rows, a1wTc, w2T, bias2[0:128] ----
__global__ __launch_bounds__(256) void k_prep(
    const float* __restrict__ W, const float* __restrict__ qz,
    const float* __restrict__ a1w, const float* __restrict__ a2w,
    const float* __restrict__ bb,
    float* __restrict__ Wef32, short* __restrict__ BT2,
    short* __restrict__ a1wTc, short* __restrict__ w2T,
    float* __restrict__ bias2) {
  int i = blockIdx.x * 256 + threadIdx.x;
  if (i < 32768) {                       // (f,e): We = W*z
    int f = i >> 7, e = i & 127;
    float g = qz[f];
    float s = 1.0f / (1.0f + expf(-g));
    float z = fminf(fmaxf(s * 1.2f - 0.1f, 0.0f), 1.0f);
    float v = W[f * 128 + e] * z;
    Wef32[f * 128 + e] = v;
    BT2[e * 256 + f] = f2bf(v);          // X-part rows of combined BT
  } else if (i < 49152) {                // a1wTc[n][k] = a1w[128+k][n]
    int t = i - 32768; int n = t >> 7, k = t & 127;
    a1wTc[n * 128 + k] = f2bf(a1w[(128 + k) * 128 + n]);
  } else if (i < 65536) {                // w2T[n][k] = a2w[k][n]
    int t = i - 49152; int n = t >> 7, k = t & 127;
    w2T[n * 128 + k] = f2bf(a2w[k * 128 + n]);
  } else if (i < 65664) {                // bias2[0:128] = b
    bias2[i - 65536] = bb[i - 65536];
  }
}

// ---- compose: BT2 Y-rows = (We @ A1n)^T, bias2[128:] = b@A1n + a1b ----
__global__ __launch_bounds__(256) void k_compose(
    const float* __restrict__ Wef32, const float* __restrict__ a1w,
    const float* __restrict__ a1b, const float* __restrict__ bb,
    short* __restrict__ BT2, float* __restrict__ bias2) {
  const int n = blockIdx.x;       // 0..127 output col of Y
  const int f = threadIdx.x;      // 0..255
  float s = 0.f;
  for (int e = 0; e < 128; ++e)
    s = fmaf(a1w[e * 128 + n], Wef32[f * 128 + e], s);
  BT2[(size_t)(128 + n) * 256 + f] = f2bf(s);
  if (f == 0) {
    float by = a1b[n];
    for (int e = 0; e < 128; ++e) by = fmaf(bb[e], a1w[e * 128 + n], by);
    bias2[128 + n] = by;
  }
}

// ---- XY GEMM v3: fp32 A tile via global_load_lds; B in registers ----
// XY[M][256] = feature[M][256] @ BT2[256][256]^T + bias2
// 64-row tile, 4 waves; wave wn owns cols wn*64..wn*64+63.
__global__ __launch_bounds__(256, 2) void k_xy(
    const float* __restrict__ feat, const short* __restrict__ BT2,
    const float* __restrict__ bias2, short* __restrict__ XY, int M) {
  __shared__ float As[64 * 256];   // 64 KiB fp32, linear [row][k]
  const int tid = threadIdx.x;
  const int mb = blockIdx.x * 64;
  const int wave = tid >> 6, lane = tid & 63;
  const int wn = wave;                        // col block
  const int l15 = lane & 15, lg = lane >> 4;

  // ---- B fragments: load once per block into registers (one L2 round-trip)
  short8 bfr[8][4];
#pragma unroll
  for (int ks = 0; ks < 8; ++ks)
#pragma unroll
    for (int j = 0; j < 4; ++j)
      bfr[ks][j] = *(const short8*)(BT2 +
          (size_t)(wn * 64 + j * 16 + l15) * 256 + (ks * 4 + lg) * 8);

  // ---- A tile: async global->LDS, no VGPR round-trip, single drain
#pragma unroll
  for (int it = 0; it < 16; ++it) {
    int r = it * 4 + wave;                    // 0..63 (wave-uniform)
    int grow = mb + r;
    if (grow >= M) grow = M - 1;
    gll16(feat + (size_t)grow * 256 + lane * 4, As + r * 256);
  }
  __syncthreads();                            // vmcnt(0) + barrier

  f32x4 acc[4][4];
#pragma unroll
  for (int i = 0; i < 4; ++i)
#pragma unroll
    for (int j = 0; j < 4; ++j) acc[i][j] = (f32x4){0.f, 0.f, 0.f, 0.f};

#pragma unroll
  for (int ks = 0; ks < 8; ++ks) {
    const int kg = ks * 4 + lg;               // 8-float k-group
#pragma unroll
    for (int i = 0; i < 4; ++i) {
      const int r = i * 16 + l15;
      const float* ap = As + r * 256 + kg * 8;
      float4 flo = *(const float4*)ap;
      float4 fhi = *(const float4*)(ap + 4);
      short8 af;
      af[0] = f2bf(flo.x); af[1] = f2bf(flo.y);
      af[2] = f2bf(flo.z); af[3] = f2bf(flo.w);
      af[4] = f2bf(fhi.x); af[5] = f2bf(fhi.y);
      af[6] = f2bf(fhi.z); af[7] = f2bf(fhi.w);
      __builtin_amdgcn_s_setprio(1);
#pragma unroll
      for (int j = 0; j < 4; ++j)
        acc[i][j] = __builtin_amdgcn_mfma_f32_16x16x32_bf16(
            af, bfr[ks][j], acc[i][j], 0, 0, 0);
      __builtin_amdgcn_s_setprio(0);
    }
  }

  float bv4[4];
#pragma unroll
  for (int j = 0; j < 4; ++j) bv4[j] = bias2[wn * 64 + j * 16 + l15];
#pragma unroll
  for (int i = 0; i < 4; ++i) {
#pragma unroll
    for (int r = 0; r < 4; ++r) {
      int row = mb + i * 16 + lg * 4 + r;
      if (row < M) {
#pragma unroll
        for (int j = 0; j < 4; ++j) {
          int col = wn * 64 + j * 16 + l15;
          XY[(size_t)row * 256 + col] = f2bf(acc[i][j][r] + bv4[j]);
        }
      }
    }
  }
}

// ---- MFMA GEMM (used for P): C = A(rows via idx, stride LDA)@BT^T + bias --
template <int K, int LDA, int LDC, bool AF32, bool OUTBF16>
__global__ __launch_bounds__(256) void k_mm(
    const void* __restrict__ Ap, const short* __restrict__ BT,
    const float* __restrict__ bias, const int* __restrict__ idx,
    void* __restrict__ Cp, int M) {
  __shared__ short As[128 * 64];
  __shared__ short Bs[128 * 64];
  const int tid = threadIdx.x;
  const int mb = blockIdx.x * 128;
  const int col0 = blockIdx.y * 128;
  const int wave = tid >> 6, lane = tid & 63;
  const int wr = wave >> 1, wc = wave & 1;
  const int l15 = lane & 15, lg = lane >> 4;

  size_t abase[4];
#pragma unroll
  for (int s = 0; s < 4; ++s) {
    int row = (tid + s * 256) >> 3;
    int grow = mb + row;
    int gr = 0;
    if (grow < M) gr = idx ? idx[grow] : grow;
    abase[s] = (size_t)gr * LDA;
  }

  f32x4 acc[4][4];
#pragma unroll
  for (int i = 0; i < 4; ++i)
#pragma unroll
    for (int j = 0; j < 4; ++j) acc[i][j] = (f32x4){0.f, 0.f, 0.f, 0.f};

  for (int k0 = 0; k0 < K; k0 += 64) {
#pragma unroll
    for (int s = 0; s < 4; ++s) {
      int q = tid + s * 256;
      int row = q >> 3, c = q & 7;
      short8 av;
      if (AF32) {
        const float* ap = (const float*)Ap + abase[s] + k0 + c * 8;
        float4 f0 = *(const float4*)ap;
        float4 f1 = *(const float4*)(ap + 4);
        av[0] = f2bf(f0.x); av[1] = f2bf(f0.y);
        av[2] = f2bf(f0.z); av[3] = f2bf(f0.w);
        av[4] = f2bf(f1.x); av[5] = f2bf(f1.y);
        av[6] = f2bf(f1.z); av[7] = f2bf(f1.w);
      } else {
        av = *(const short8*)((const short*)Ap + abase[s] + k0 + c * 8);
      }
      *(short8*)(As + row * 64 + 8 * (c ^ (row & 7))) = av;
      short8 bv = *(const short8*)(BT + (size_t)(col0 + row) * K + k0 + c * 8);
      *(short8*)(Bs + row * 64 + 8 * (c ^ (row & 7))) = bv;
    }
    __syncthreads();
#pragma unroll
    for (int ks = 0; ks < 2; ++ks) {
      int c = ks * 4 + lg;
      short8 af[4], bfv[4];
#pragma unroll
      for (int i = 0; i < 4; ++i) {
        int r = wr * 64 + i * 16 + l15;
        af[i] = *(short8*)(As + r * 64 + 8 * (c ^ (r & 7)));
        int n = wc * 64 + i * 16 + l15;
        bfv[i] = *(short8*)(Bs + n * 64 + 8 * (c ^ (n & 7)));
      }
#pragma unroll
      for (int i = 0; i < 4; ++i)
#pragma unroll
        for (int j = 0; j < 4; ++j)
          acc[i][j] = __builtin_amdgcn_mfma_f32_16x16x32_bf16(
              af[i], bfv[j], acc[i][j], 0, 0, 0);
    }
    __syncthreads();
  }

  float bv4[4];
#pragma unroll
  for (int j = 0; j < 4; ++j) {
    int col = wc * 64 + j * 16 + l15;
    bv4[j] = bias ? bias[col0 + col] : 0.f;
  }
#pragma unroll
  for (int i = 0; i < 4; ++i) {
#pragma unroll
    for (int r = 0; r < 4; ++r) {
      int row = mb + wr * 64 + i * 16 + lg * 4 + r;
      if (row < M) {
#pragma unroll
        for (int j = 0; j < 4; ++j) {
          int col = wc * 64 + j * 16 + l15;
          float v = acc[i][j][r] + bv4[j];
          if (OUTBF16)
            ((short*)Cp)[(size_t)row * LDC + col0 + col] = f2bf(v);
          else
            ((float*)Cp)[(size_t)row * LDC + col0 + col] = v;
        }
      }
    }
  }
}

// ---- fused attention v4: one wave == one center, batched round-trips ----
__global__ __launch_bounds__(256) void k_attn4(
    const short* __restrict__ XY, const float* __restrict__ P,
    const int* __restrict__ nodes, const int* __restrict__ nidx,
    const int* __restrict__ nmask, const short* __restrict__ w2T,
    const float* __restrict__ b2, const float* __restrict__ w3,
    const float* __restrict__ b3, float* __restrict__ out) {
  __shared__ int ni_s[4][32];
  __shared__ float sc_s[4][32];
  __shared__ float att_s[4][32];
  const int tid = threadIdx.x;
  const int wave = tid >> 6, lane = tid & 63;
  const int b = blockIdx.x * 4 + wave;      // this wave's center
  const int l15 = lane & 15, lg = lane >> 4;

  if (lane < 32) ni_s[wave][lane] = nidx[b * DD + lane];

  // ---- round-trip 2: issue EVERYTHING whose address depends only on nidx
  const int m = nmask[(size_t)b * DD + (lane & 31)];     // mask (early)
  const int nid0 = ni_s[wave][l15];
  const int nid1 = ni_s[wave][16 + l15];
  const short* yr0 = XY + (size_t)nid0 * 256 + 128;      // Y half
  const short* yr1 = XY + (size_t)nid1 * 256 + 128;
  short8 y0v[4], y1v[4];
#pragma unroll
  for (int ks = 0; ks < 4; ++ks) {
    const int k0 = ks * 32 + lg * 8;
    y0v[ks] = *(const short8*)(yr0 + k0);
    y1v[ks] = *(const short8*)(yr1 + k0);
  }
  unsigned xv[32];                                        // X prefetch
#pragma unroll
  for (int d = 0; d < 32; ++d)
    xv[d] = *(const unsigned*)(XY + (size_t)ni_s[wave][d] * 256 + 2 * lane);

  const float* pr = P + (size_t)b * EE;

  f32x4 acc[2][8];
#pragma unroll
  for (int i = 0; i < 2; ++i)
#pragma unroll
    for (int j = 0; j < 8; ++j) acc[i][j] = (f32x4){0.f, 0.f, 0.f, 0.f};

#pragma unroll
  for (int ks = 0; ks < 4; ++ks) {
    const int k0 = ks * 32 + lg * 8;
    float4 pa = *(const float4*)(pr + k0);
    float4 pb = *(const float4*)(pr + k0 + 4);
    float pf[8] = {pa.x, pa.y, pa.z, pa.w, pb.x, pb.y, pb.z, pb.w};
    short8 a0, a1;
#pragma unroll
    for (int e = 0; e < 8; ++e) {
      a0[e] = f2bf(fmaxf(bf2f(y0v[ks][e]) + pf[e], 0.f));
      a1[e] = f2bf(fmaxf(bf2f(y1v[ks][e]) + pf[e], 0.f));
    }
    short8 bfv[8];
#pragma unroll
    for (int j = 0; j < 8; ++j)
      bfv[j] = *(const short8*)(w2T + (size_t)(j * 16 + l15) * EE + k0);
    __builtin_amdgcn_s_setprio(1);
#pragma unroll
    for (int j = 0; j < 8; ++j) {
      acc[0][j] = __builtin_amdgcn_mfma_f32_16x16x32_bf16(a0, bfv[j],
                                                          acc[0][j], 0, 0, 0);
      acc[1][j] = __builtin_amdgcn_mfma_f32_16x16x32_bf16(a1, bfv[j],
                                                          acc[1][j], 0, 0, 0);
    }
    __builtin_amdgcn_s_setprio(0);
  }

  // scores: s[row] = sum_col relu(h2[row][col]+b2[col]) * w3[col]
  float b2v[8], w3v[8];
#pragma unroll
  for (int j = 0; j < 8; ++j) {
    int col = j * 16 + l15;
    b2v[j] = b2[col];
    w3v[j] = w3[col];
  }
  float part[2][4];
#pragma unroll
  for (int i = 0; i < 2; ++i)
#pragma unroll
    for (int r = 0; r < 4; ++r) {
      float s = 0.f;
#pragma unroll
      for (int j = 0; j < 8; ++j)
        s += fmaxf(acc[i][j][r] + b2v[j], 0.f) * w3v[j];
      part[i][r] = s;
    }
#pragma unroll
  for (int off = 1; off <= 8; off <<= 1) {
#pragma unroll
    for (int i = 0; i < 2; ++i)
#pragma unroll
      for (int r = 0; r < 4; ++r) part[i][r] += __shfl_xor(part[i][r], off);
  }
  if (l15 == 0) {
#pragma unroll
    for (int i = 0; i < 2; ++i)
#pragma unroll
      for (int r = 0; r < 4; ++r)
        sc_s[wave][i * 16 + lg * 4 + r] = part[i][r];
  }

  // softmax over 32 rows (duplicated in both 32-lane halves)
  const int row = lane & 31;
  float s = sc_s[wave][row] + b3[0];
  if (!m) s = -1e30f;
  float mx = s;
#pragma unroll
  for (int off = 1; off <= 16; off <<= 1) mx = fmaxf(mx, __shfl_xor(mx, off));
  float e = expf(s - mx);
  float sum = e;
#pragma unroll
  for (int off = 1; off <= 16; off <<= 1) sum += __shfl_xor(sum, off);
  if (lane < 32) att_s[wave][row] = e / sum;
  const bool has = (__ballot(m != 0) != 0ull);

  // agg on prefetched X
  float a0 = 0.f, a1 = 0.f;
  if (has) {
#pragma unroll
    for (int d = 0; d < 32; ++d) {
      float a = att_s[wave][d];
      a0 += a * bf2f((short)(xv[d] & 0xffffu));
      a1 += a * bf2f((short)(xv[d] >> 16));
    }
  } else {
    const short* xr = XY + (size_t)nodes[b] * 256;
    unsigned x2 = *(const unsigned*)(xr + 2 * lane);
    a0 = bf2f((short)(x2 & 0xffffu));
    a1 = bf2f((short)(x2 >> 16));
  }
  *(float2*)(out + (size_t)b * EE + 2 * lane) = make_float2(a0, a1);
}

extern "C" void kernel_launch(void* const* d_in, const int* in_sizes, int n_in,
                              void* d_out, int out_size, void* d_ws,
                              size_t ws_size, hipStream_t stream) {
  const int* nodes = (const int*)d_in[0];
  const int* nidx = (const int*)d_in[1];
  const int* nmask = (const int*)d_in[2];
  const float* feature = (const float*)d_in[3];
  const float* W = (const float*)d_in[4];
  const float* bb = (const float*)d_in[5];
  const float* qz = (const float*)d_in[6];
  const float* a1w = (const float*)d_in[7];
  const float* a1b = (const float*)d_in[8];
  const float* a2w = (const float*)d_in[9];
  const float* a2b = (const float*)d_in[10];
  const float* a3w = (const float*)d_in[11];
  const float* a3b = (const float*)d_in[12];
  float* out = (float*)d_out;

  char* ws = (char*)d_ws;
  short* BT2   = (short*)(ws);                       // 128 KiB [256][256] bf16
  float* Wef32 = (float*)(ws + 131072);              // 128 KiB
  short* a1wTc = (short*)(ws + 262144);              // 32 KiB
  short* w2T   = (short*)(ws + 294912);              // 32 KiB
  float* bias2 = (float*)(ws + 327680);              // 1 KiB
  short* XYb   = (short*)(ws + 524288);              // 51.2 MB bf16 [N][256]
  float* Pv    = (float*)(ws + 524288 + 51200000);   // 5.12 MB fp32

  k_prep<<<257, 256, 0, stream>>>(W, qz, a1w, a2w, bb, Wef32, BT2, a1wTc, w2T,
                                  bias2);
  k_compose<<<128, 256, 0, stream>>>(Wef32, a1w, a1b, bb, BT2, bias2);
  // XY = feature @ [We|Wy] + bias2    [100000,256]x[256,256] -> bf16
  k_xy<<<(NN + 63) / 64, 256, 0, stream>>>(feature, BT2, bias2, XYb, NN);
  // P = X[nodes] @ att1_w[128:]       [10000,128]x[128,128] -> fp32
  k_mm<128, 256, 128, false, false><<<dim3((BB_ + 127) / 128, 1), 256, 0,
                                      stream>>>(XYb, a1wTc, nullptr, nodes, Pv,
                                                BB_);
  // fused attention + aggregation (1 wave per center, batched gathers)
  k_attn4<<<BB_ / 4, 256, 0, stream>>>(XYb, Pv, nodes, nidx, nmask, w2T, a2b,
                                       a3w, a3b, out);
}

// Round 7
// 141.613 us; speedup vs baseline: 1.2217x; 1.2217x over previous
//
#include <hip/hip_runtime.h>
#include <hip/hip_bf16.h>
#include <math.h>

#define NN 100000
#define FF 256
#define EE 128
#define BB_ 10000
#define DD 32

typedef __attribute__((ext_vector_type(8))) short short8;
typedef __attribute__((ext_vector_type(4))) float f32x4;

__device__ __forceinline__ short f2bf(float f) {
  __hip_bfloat16 h = __float2bfloat16(f);   // HW RNE cvt
  union { __hip_bfloat16 h; short s; } u; u.h = h;
  return u.s;
}
__device__ __forceinline__ float bf2f(short s) {
  union { unsigned u; float f; } v;
  v.u = ((unsigned)(unsigned short)s) << 16;
  return v.f;
}

// async global->LDS, 16B per lane; LDS dest = wave-uniform base + lane*16
__device__ __forceinline__ void gll16(const float* g, float* lds) {
  __builtin_amdgcn_global_load_lds(
      (const __attribute__((address_space(1))) unsigned int*)g,
      (__attribute__((address_space(3))) unsigned int*)lds, 16, 0, 0);
}

// ---- prep: Wef32 = W*z (fp32), BT2 X-rows, a1wTc, w2T, bias2[0:128] ----
__global__ __launch_bounds__(256) void k_prep(
    const float* __restrict__ W, const float* __restrict__ qz,
    const float* __restrict__ a1w, const float* __restrict__ a2w,
    const float* __restrict__ bb,
    float* __restrict__ Wef32, short* __restrict__ BT2,
    short* __restrict__ a1wTc, short* __restrict__ w2T,
    float* __restrict__ bias2) {
  int i = blockIdx.x * 256 + threadIdx.x;
  if (i < 32768) {                       // (f,e): We = W*z
    int f = i >> 7, e = i & 127;
    float g = qz[f];
    float s = 1.0f / (1.0f + expf(-g));
    float z = fminf(fmaxf(s * 1.2f - 0.1f, 0.0f), 1.0f);
    float v = W[f * 128 + e] * z;
    Wef32[f * 128 + e] = v;
    BT2[e * 256 + f] = f2bf(v);          // X-part rows of combined BT
  } else if (i < 49152) {                // a1wTc[n][k] = a1w[128+k][n]
    int t = i - 32768; int n = t >> 7, k = t & 127;
    a1wTc[n * 128 + k] = f2bf(a1w[(128 + k) * 128 + n]);
  } else if (i < 65536) {                // w2T[n][k] = a2w[k][n]
    int t = i - 49152; int n = t >> 7, k = t & 127;
    w2T[n * 128 + k] = f2bf(a2w[k * 128 + n]);
  } else if (i < 65664) {                // bias2[0:128] = b
    bias2[i - 65536] = bb[i - 65536];
  }
}

// ---- compose: BT2 Y-rows = (We @ A1n)^T, bias2[128:] = b@A1n + a1b ----
__global__ __launch_bounds__(256) void k_compose(
    const float* __restrict__ Wef32, const float* __restrict__ a1w,
    const float* __restrict__ a1b, const float* __restrict__ bb,
    short* __restrict__ BT2, float* __restrict__ bias2) {
  const int n = blockIdx.x;       // 0..127 output col of Y
  const int f = threadIdx.x;      // 0..255
  float s = 0.f;
  for (int e = 0; e < 128; ++e)
    s = fmaf(a1w[e * 128 + n], Wef32[f * 128 + e], s);
  BT2[(size_t)(128 + n) * 256 + f] = f2bf(s);
  if (f == 0) {
    float by = a1b[n];
    for (int e = 0; e < 128; ++e) by = fmaf(bb[e], a1w[e * 128 + n], by);
    bias2[128 + n] = by;
  }
}

// ---- XY GEMM v4: gll staging with source-side chunk swizzle ----
// XY[M][256] = feature[M][256] @ BT2[256][256]^T + bias2
// 64-row tile, 4 waves; wave wn owns cols wn*64..wn*64+63.
// LDS chunk c of row r holds GLOBAL chunk (c ^ (r&7)); reads XOR the same.
__global__ __launch_bounds__(256, 2) void k_xy(
    const float* __restrict__ feat, const short* __restrict__ BT2,
    const float* __restrict__ bias2, short* __restrict__ XY, int M) {
  __shared__ float As[64 * 256];   // 64 KiB fp32, linear rows, swz chunks
  const int tid = threadIdx.x;
  const int mb = blockIdx.x * 64;
  const int wave = tid >> 6, lane = tid & 63;
  const int wn = wave;                        // col block
  const int l15 = lane & 15, lg = lane >> 4;

  // ---- A tile first (HBM latency starts earliest): async global->LDS.
  // gll writes LDS chunk `lane`; source fetches global chunk lane^(r&7).
#pragma unroll
  for (int it = 0; it < 16; ++it) {
    int r = it * 4 + wave;                    // 0..63 (wave-uniform)
    int grow = mb + r;
    if (grow >= M) grow = M - 1;
    gll16(feat + (size_t)grow * 256 + ((lane ^ (r & 7)) * 4), As + r * 256);
  }

  // ---- B fragments: load once per block into registers (L2 round-trip)
  short8 bfr[8][4];
#pragma unroll
  for (int ks = 0; ks < 8; ++ks)
#pragma unroll
    for (int j = 0; j < 4; ++j)
      bfr[ks][j] = *(const short8*)(BT2 +
          (size_t)(wn * 64 + j * 16 + l15) * 256 + (ks * 4 + lg) * 8);

  __syncthreads();                            // vmcnt(0) + barrier

  f32x4 acc[4][4];
#pragma unroll
  for (int i = 0; i < 4; ++i)
#pragma unroll
    for (int j = 0; j < 4; ++j) acc[i][j] = (f32x4){0.f, 0.f, 0.f, 0.f};

#pragma unroll
  for (int ks = 0; ks < 8; ++ks) {
    const int kg = ks * 4 + lg;               // 8-float k-group
#pragma unroll
    for (int i = 0; i < 4; ++i) {
      const int r = i * 16 + l15;
      const int sw = r & 7;
      const int c0 = (2 * kg) ^ sw;           // 16B chunk of k kg*8..+3
      const int c1 = (2 * kg + 1) ^ sw;       // 16B chunk of k kg*8+4..+7
      float4 flo = *(const float4*)(As + r * 256 + c0 * 4);
      float4 fhi = *(const float4*)(As + r * 256 + c1 * 4);
      short8 af;
      af[0] = f2bf(flo.x); af[1] = f2bf(flo.y);
      af[2] = f2bf(flo.z); af[3] = f2bf(flo.w);
      af[4] = f2bf(fhi.x); af[5] = f2bf(fhi.y);
      af[6] = f2bf(fhi.z); af[7] = f2bf(fhi.w);
      __builtin_amdgcn_s_setprio(1);
#pragma unroll
      for (int j = 0; j < 4; ++j)
        acc[i][j] = __builtin_amdgcn_mfma_f32_16x16x32_bf16(
            af, bfr[ks][j], acc[i][j], 0, 0, 0);
      __builtin_amdgcn_s_setprio(0);
    }
  }

  float bv4[4];
#pragma unroll
  for (int j = 0; j < 4; ++j) bv4[j] = bias2[wn * 64 + j * 16 + l15];
#pragma unroll
  for (int i = 0; i < 4; ++i) {
#pragma unroll
    for (int r = 0; r < 4; ++r) {
      int row = mb + i * 16 + lg * 4 + r;
      if (row < M) {
#pragma unroll
        for (int j = 0; j < 4; ++j) {
          int col = wn * 64 + j * 16 + l15;
          XY[(size_t)row * 256 + col] = f2bf(acc[i][j][r] + bv4[j]);
        }
      }
    }
  }
}

// ---- MFMA GEMM (used for P): C = A(rows via idx, stride LDA)@BT^T + bias --
template <int K, int LDA, int LDC, bool AF32, bool OUTBF16>
__global__ __launch_bounds__(256) void k_mm(
    const void* __restrict__ Ap, const short* __restrict__ BT,
    const float* __restrict__ bias, const int* __restrict__ idx,
    void* __restrict__ Cp, int M) {
  __shared__ short As[128 * 64];
  __shared__ short Bs[128 * 64];
  const int tid = threadIdx.x;
  const int mb = blockIdx.x * 128;
  const int col0 = blockIdx.y * 128;
  const int wave = tid >> 6, lane = tid & 63;
  const int wr = wave >> 1, wc = wave & 1;
  const int l15 = lane & 15, lg = lane >> 4;

  size_t abase[4];
#pragma unroll
  for (int s = 0; s < 4; ++s) {
    int row = (tid + s * 256) >> 3;
    int grow = mb + row;
    int gr = 0;
    if (grow < M) gr = idx ? idx[grow] : grow;
    abase[s] = (size_t)gr * LDA;
  }

  f32x4 acc[4][4];
#pragma unroll
  for (int i = 0; i < 4; ++i)
#pragma unroll
    for (int j = 0; j < 4; ++j) acc[i][j] = (f32x4){0.f, 0.f, 0.f, 0.f};

  for (int k0 = 0; k0 < K; k0 += 64) {
#pragma unroll
    for (int s = 0; s < 4; ++s) {
      int q = tid + s * 256;
      int row = q >> 3, c = q & 7;
      short8 av;
      if (AF32) {
        const float* ap = (const float*)Ap + abase[s] + k0 + c * 8;
        float4 f0 = *(const float4*)ap;
        float4 f1 = *(const float4*)(ap + 4);
        av[0] = f2bf(f0.x); av[1] = f2bf(f0.y);
        av[2] = f2bf(f0.z); av[3] = f2bf(f0.w);
        av[4] = f2bf(f1.x); av[5] = f2bf(f1.y);
        av[6] = f2bf(f1.z); av[7] = f2bf(f1.w);
      } else {
        av = *(const short8*)((const short*)Ap + abase[s] + k0 + c * 8);
      }
      *(short8*)(As + row * 64 + 8 * (c ^ (row & 7))) = av;
      short8 bv = *(const short8*)(BT + (size_t)(col0 + row) * K + k0 + c * 8);
      *(short8*)(Bs + row * 64 + 8 * (c ^ (row & 7))) = bv;
    }
    __syncthreads();
#pragma unroll
    for (int ks = 0; ks < 2; ++ks) {
      int c = ks * 4 + lg;
      short8 af[4], bfv[4];
#pragma unroll
      for (int i = 0; i < 4; ++i) {
        int r = wr * 64 + i * 16 + l15;
        af[i] = *(short8*)(As + r * 64 + 8 * (c ^ (r & 7)));
        int n = wc * 64 + i * 16 + l15;
        bfv[i] = *(short8*)(Bs + n * 64 + 8 * (c ^ (n & 7)));
      }
#pragma unroll
      for (int i = 0; i < 4; ++i)
#pragma unroll
        for (int j = 0; j < 4; ++j)
          acc[i][j] = __builtin_amdgcn_mfma_f32_16x16x32_bf16(
              af[i], bfv[j], acc[i][j], 0, 0, 0);
    }
    __syncthreads();
  }

  float bv4[4];
#pragma unroll
  for (int j = 0; j < 4; ++j) {
    int col = wc * 64 + j * 16 + l15;
    bv4[j] = bias ? bias[col0 + col] : 0.f;
  }
#pragma unroll
  for (int i = 0; i < 4; ++i) {
#pragma unroll
    for (int r = 0; r < 4; ++r) {
      int row = mb + wr * 64 + i * 16 + lg * 4 + r;
      if (row < M) {
#pragma unroll
        for (int j = 0; j < 4; ++j) {
          int col = wc * 64 + j * 16 + l15;
          float v = acc[i][j][r] + bv4[j];
          if (OUTBF16)
            ((short*)Cp)[(size_t)row * LDC + col0 + col] = f2bf(v);
          else
            ((float*)Cp)[(size_t)row * LDC + col0 + col] = v;
        }
      }
    }
  }
}

// ---- fused attention v4: one wave == one center, batched round-trips ----
__global__ __launch_bounds__(256) void k_attn4(
    const short* __restrict__ XY, const float* __restrict__ P,
    const int* __restrict__ nodes, const int* __restrict__ nidx,
    const int* __restrict__ nmask, const short* __restrict__ w2T,
    const float* __restrict__ b2, const float* __restrict__ w3,
    const float* __restrict__ b3, float* __restrict__ out) {
  __shared__ int ni_s[4][32];
  __shared__ float sc_s[4][32];
  __shared__ float att_s[4][32];
  const int tid = threadIdx.x;
  const int wave = tid >> 6, lane = tid & 63;
  const int b = blockIdx.x * 4 + wave;      // this wave's center
  const int l15 = lane & 15, lg = lane >> 4;

  if (lane < 32) ni_s[wave][lane] = nidx[b * DD + lane];

  // ---- round-trip 2: issue EVERYTHING whose address depends only on nidx
  const int m = nmask[(size_t)b * DD + (lane & 31)];     // mask (early)
  const int nid0 = ni_s[wave][l15];
  const int nid1 = ni_s[wave][16 + l15];
  const short* yr0 = XY + (size_t)nid0 * 256 + 128;      // Y half
  const short* yr1 = XY + (size_t)nid1 * 256 + 128;
  short8 y0v[4], y1v[4];
#pragma unroll
  for (int ks = 0; ks < 4; ++ks) {
    const int k0 = ks * 32 + lg * 8;
    y0v[ks] = *(const short8*)(yr0 + k0);
    y1v[ks] = *(const short8*)(yr1 + k0);
  }
  unsigned xv[32];                                        // X prefetch
#pragma unroll
  for (int d = 0; d < 32; ++d)
    xv[d] = *(const unsigned*)(XY + (size_t)ni_s[wave][d] * 256 + 2 * lane);

  const float* pr = P + (size_t)b * EE;

  f32x4 acc[2][8];
#pragma unroll
  for (int i = 0; i < 2; ++i)
#pragma unroll
    for (int j = 0; j < 8; ++j) acc[i][j] = (f32x4){0.f, 0.f, 0.f, 0.f};

#pragma unroll
  for (int ks = 0; ks < 4; ++ks) {
    const int k0 = ks * 32 + lg * 8;
    float4 pa = *(const float4*)(pr + k0);
    float4 pb = *(const float4*)(pr + k0 + 4);
    float pf[8] = {pa.x, pa.y, pa.z, pa.w, pb.x, pb.y, pb.z, pb.w};
    short8 a0, a1;
#pragma unroll
    for (int e = 0; e < 8; ++e) {
      a0[e] = f2bf(fmaxf(bf2f(y0v[ks][e]) + pf[e], 0.f));
      a1[e] = f2bf(fmaxf(bf2f(y1v[ks][e]) + pf[e], 0.f));
    }
    short8 bfv[8];
#pragma unroll
    for (int j = 0; j < 8; ++j)
      bfv[j] = *(const short8*)(w2T + (size_t)(j * 16 + l15) * EE + k0);
    __builtin_amdgcn_s_setprio(1);
#pragma unroll
    for (int j = 0; j < 8; ++j) {
      acc[0][j] = __builtin_amdgcn_mfma_f32_16x16x32_bf16(a0, bfv[j],
                                                          acc[0][j], 0, 0, 0);
      acc[1][j] = __builtin_amdgcn_mfma_f32_16x16x32_bf16(a1, bfv[j],
                                                          acc[1][j], 0, 0, 0);
    }
    __builtin_amdgcn_s_setprio(0);
  }

  // scores: s[row] = sum_col relu(h2[row][col]+b2[col]) * w3[col]
  float b2v[8], w3v[8];
#pragma unroll
  for (int j = 0; j < 8; ++j) {
    int col = j * 16 + l15;
    b2v[j] = b2[col];
    w3v[j] = w3[col];
  }
  float part[2][4];
#pragma unroll
  for (int i = 0; i < 2; ++i)
#pragma unroll
    for (int r = 0; r < 4; ++r) {
      float s = 0.f;
#pragma unroll
      for (int j = 0; j < 8; ++j)
        s += fmaxf(acc[i][j][r] + b2v[j], 0.f) * w3v[j];
      part[i][r] = s;
    }
#pragma unroll
  for (int off = 1; off <= 8; off <<= 1) {
#pragma unroll
    for (int i = 0; i < 2; ++i)
#pragma unroll
      for (int r = 0; r < 4; ++r) part[i][r] += __shfl_xor(part[i][r], off);
  }
  if (l15 == 0) {
#pragma unroll
    for (int i = 0; i < 2; ++i)
#pragma unroll
      for (int r = 0; r < 4; ++r)
        sc_s[wave][i * 16 + lg * 4 + r] = part[i][r];
  }

  // softmax over 32 rows (duplicated in both 32-lane halves)
  const int row = lane & 31;
  float s = sc_s[wave][row] + b3[0];
  if (!m) s = -1e30f;
  float mx = s;
#pragma unroll
  for (int off = 1; off <= 16; off <<= 1) mx = fmaxf(mx, __shfl_xor(mx, off));
  float e = expf(s - mx);
  float sum = e;
#pragma unroll
  for (int off = 1; off <= 16; off <<= 1) sum += __shfl_xor(sum, off);
  if (lane < 32) att_s[wave][row] = e / sum;
  const bool has = (__ballot(m != 0) != 0ull);

  // agg on prefetched X
  float a0 = 0.f, a1 = 0.f;
  if (has) {
#pragma unroll
    for (int d = 0; d < 32; ++d) {
      float a = att_s[wave][d];
      a0 += a * bf2f((short)(xv[d] & 0xffffu));
      a1 += a * bf2f((short)(xv[d] >> 16));
    }
  } else {
    const short* xr = XY + (size_t)nodes[b] * 256;
    unsigned x2 = *(const unsigned*)(xr + 2 * lane);
    a0 = bf2f((short)(x2 & 0xffffu));
    a1 = bf2f((short)(x2 >> 16));
  }
  *(float2*)(out + (size_t)b * EE + 2 * lane) = make_float2(a0, a1);
}

extern "C" void kernel_launch(void* const* d_in, const int* in_sizes, int n_in,
                              void* d_out, int out_size, void* d_ws,
                              size_t ws_size, hipStream_t stream) {
  const int* nodes = (const int*)d_in[0];
  const int* nidx = (const int*)d_in[1];
  const int* nmask = (const int*)d_in[2];
  const float* feature = (const float*)d_in[3];
  const float* W = (const float*)d_in[4];
  const float* bb = (const float*)d_in[5];
  const float* qz = (const float*)d_in[6];
  const float* a1w = (const float*)d_in[7];
  const float* a1b = (const float*)d_in[8];
  const float* a2w = (const float*)d_in[9];
  const float* a2b = (const float*)d_in[10];
  const float* a3w = (const float*)d_in[11];
  const float* a3b = (const float*)d_in[12];
  float* out = (float*)d_out;

  char* ws = (char*)d_ws;
  short* BT2   = (short*)(ws);                       // 128 KiB [256][256] bf16
  float* Wef32 = (float*)(ws + 131072);              // 128 KiB
  short* a1wTc = (short*)(ws + 262144);              // 32 KiB
  short* w2T   = (short*)(ws + 294912);              // 32 KiB
  float* bias2 = (float*)(ws + 327680);              // 1 KiB
  short* XYb   = (short*)(ws + 524288);              // 51.2 MB bf16 [N][256]
  float* Pv    = (float*)(ws + 524288 + 51200000);   // 5.12 MB fp32

  k_prep<<<257, 256, 0, stream>>>(W, qz, a1w, a2w, bb, Wef32, BT2, a1wTc, w2T,
                                  bias2);
  k_compose<<<128, 256, 0, stream>>>(Wef32, a1w, a1b, bb, BT2, bias2);
  // XY = feature @ [We|Wy] + bias2    [100000,256]x[256,256] -> bf16
  k_xy<<<(NN + 63) / 64, 256, 0, stream>>>(feature, BT2, bias2, XYb, NN);
  // P = X[nodes] @ att1_w[128:]       [10000,128]x[128,128] -> fp32
  k_mm<128, 256, 128, false, false><<<dim3((BB_ + 127) / 128, 1), 256, 0,
                                      stream>>>(XYb, a1wTc, nullptr, nodes, Pv,
                                                BB_);
  // fused attention + aggregation (1 wave per center, batched gathers)
  k_attn4<<<BB_ / 4, 256, 0, stream>>>(XYb, Pv, nodes, nidx, nmask, w2T, a2b,
                                       a3w, a3b, out);
}

// Round 8
// 139.906 us; speedup vs baseline: 1.2366x; 1.0122x over previous
//
#include <hip/hip_runtime.h>
#include <hip/hip_bf16.h>
#include <math.h>

#define NN 100000
#define FF 256
#define EE 128
#define BB_ 10000
#define DD 32

typedef __attribute__((ext_vector_type(8))) short short8;
typedef __attribute__((ext_vector_type(4))) float f32x4;

__device__ __forceinline__ short f2bf(float f) {
  __hip_bfloat16 h = __float2bfloat16(f);   // HW RNE cvt
  union { __hip_bfloat16 h; short s; } u; u.h = h;
  return u.s;
}
__device__ __forceinline__ float bf2f(short s) {
  union { unsigned u; float f; } v;
  v.u = ((unsigned)(unsigned short)s) << 16;
  return v.f;
}

// async global->LDS, 16B per lane; LDS dest = wave-uniform base + lane*16
__device__ __forceinline__ void gll16(const float* g, float* lds) {
  __builtin_amdgcn_global_load_lds(
      (const __attribute__((address_space(1))) unsigned int*)g,
      (__attribute__((address_space(3))) unsigned int*)lds, 16, 0, 0);
}

// ---- prep: Wef32 = W*z (fp32), BT2 X-rows, a1wTc, w2T, bias2[0:128] ----
__global__ __launch_bounds__(256) void k_prep(
    const float* __restrict__ W, const float* __restrict__ qz,
    const float* __restrict__ a1w, const float* __restrict__ a2w,
    const float* __restrict__ bb,
    float* __restrict__ Wef32, short* __restrict__ BT2,
    short* __restrict__ a1wTc, short* __restrict__ w2T,
    float* __restrict__ bias2) {
  int i = blockIdx.x * 256 + threadIdx.x;
  if (i < 32768) {                       // (f,e): We = W*z
    int f = i >> 7, e = i & 127;
    float g = qz[f];
    float s = 1.0f / (1.0f + expf(-g));
    float z = fminf(fmaxf(s * 1.2f - 0.1f, 0.0f), 1.0f);
    float v = W[f * 128 + e] * z;
    Wef32[f * 128 + e] = v;
    BT2[e * 256 + f] = f2bf(v);          // X-part rows of combined BT
  } else if (i < 49152) {                // a1wTc[n][k] = a1w[128+k][n]
    int t = i - 32768; int n = t >> 7, k = t & 127;
    a1wTc[n * 128 + k] = f2bf(a1w[(128 + k) * 128 + n]);
  } else if (i < 65536) {                // w2T[n][k] = a2w[k][n]
    int t = i - 49152; int n = t >> 7, k = t & 127;
    w2T[n * 128 + k] = f2bf(a2w[k * 128 + n]);
  } else if (i < 65664) {                // bias2[0:128] = b
    bias2[i - 65536] = bb[i - 65536];
  }
}

// ---- compose: BT2 Y-rows = (We @ A1n)^T, bias2[128:] = b@A1n + a1b ----
__global__ __launch_bounds__(256) void k_compose(
    const float* __restrict__ Wef32, const float* __restrict__ a1w,
    const float* __restrict__ a1b, const float* __restrict__ bb,
    short* __restrict__ BT2, float* __restrict__ bias2) {
  const int n = blockIdx.x;       // 0..127 output col of Y
  const int f = threadIdx.x;      // 0..255
  float s = 0.f;
  for (int e = 0; e < 128; ++e)
    s = fmaf(a1w[e * 128 + n], Wef32[f * 128 + e], s);
  BT2[(size_t)(128 + n) * 256 + f] = f2bf(s);
  if (f == 0) {
    float by = a1b[n];
    for (int e = 0; e < 128; ++e) by = fmaf(bb[e], a1w[e * 128 + n], by);
    bias2[128 + n] = by;
  }
}

// ---- XY GEMM v5: gll staging + source-side chunk swizzle; B PINNED in regs
// XY[M][256] = feature[M][256] @ BT2[256][256]^T + bias2
// 64-row tile, 4 waves; wave wn owns cols wn*64..wn*64+63.
// LDS chunk c of row r holds GLOBAL chunk (c ^ (r&7)); reads XOR the same.
// waves_per_eu(2,2): 2 waves/SIMD matches the LDS limit (2 blocks/CU) and
// gives the allocator the full 256-VGPR budget so bfr[] stays resident.
__global__ __attribute__((amdgpu_flat_work_group_size(256, 256),
                          amdgpu_waves_per_eu(2, 2))) void k_xy(
    const float* __restrict__ feat, const short* __restrict__ BT2,
    const float* __restrict__ bias2, short* __restrict__ XY, int M) {
  __shared__ float As[64 * 256];   // 64 KiB fp32, linear rows, swz chunks
  const int tid = threadIdx.x;
  const int mb = blockIdx.x * 64;
  const int wave = tid >> 6, lane = tid & 63;
  const int wn = wave;                        // col block
  const int l15 = lane & 15, lg = lane >> 4;

  // ---- A tile first (HBM latency starts earliest): async global->LDS.
  // gll writes LDS chunk `lane`; source fetches global chunk lane^(r&7).
#pragma unroll
  for (int it = 0; it < 16; ++it) {
    int r = it * 4 + wave;                    // 0..63 (wave-uniform)
    int grow = mb + r;
    if (grow >= M) grow = M - 1;
    gll16(feat + (size_t)grow * 256 + ((lane ^ (r & 7)) * 4), As + r * 256);
  }

  // ---- B fragments: load once per block into registers (L2 round-trip)
  short8 bfr[8][4];
#pragma unroll
  for (int ks = 0; ks < 8; ++ks)
#pragma unroll
    for (int j = 0; j < 4; ++j)
      bfr[ks][j] = *(const short8*)(BT2 +
          (size_t)(wn * 64 + j * 16 + l15) * 256 + (ks * 4 + lg) * 8);
  // pin: opaque use prevents the scheduler from sinking/remat'ing the loads
#pragma unroll
  for (int ks = 0; ks < 8; ++ks)
#pragma unroll
    for (int j = 0; j < 4; ++j)
      asm volatile("" : "+v"(bfr[ks][j]));

  __syncthreads();                            // vmcnt(0) + barrier

  f32x4 acc[4][4];
#pragma unroll
  for (int i = 0; i < 4; ++i)
#pragma unroll
    for (int j = 0; j < 4; ++j) acc[i][j] = (f32x4){0.f, 0.f, 0.f, 0.f};

#pragma unroll
  for (int ks = 0; ks < 8; ++ks) {
    const int kg = ks * 4 + lg;               // 8-float k-group
#pragma unroll
    for (int i = 0; i < 4; ++i) {
      const int r = i * 16 + l15;
      const int sw = r & 7;
      const int c0 = (2 * kg) ^ sw;           // 16B chunk of k kg*8..+3
      const int c1 = (2 * kg + 1) ^ sw;       // 16B chunk of k kg*8+4..+7
      float4 flo = *(const float4*)(As + r * 256 + c0 * 4);
      float4 fhi = *(const float4*)(As + r * 256 + c1 * 4);
      short8 af;
      af[0] = f2bf(flo.x); af[1] = f2bf(flo.y);
      af[2] = f2bf(flo.z); af[3] = f2bf(flo.w);
      af[4] = f2bf(fhi.x); af[5] = f2bf(fhi.y);
      af[6] = f2bf(fhi.z); af[7] = f2bf(fhi.w);
      __builtin_amdgcn_s_setprio(1);
#pragma unroll
      for (int j = 0; j < 4; ++j)
        acc[i][j] = __builtin_amdgcn_mfma_f32_16x16x32_bf16(
            af, bfr[ks][j], acc[i][j], 0, 0, 0);
      __builtin_amdgcn_s_setprio(0);
    }
  }

  float bv4[4];
#pragma unroll
  for (int j = 0; j < 4; ++j) bv4[j] = bias2[wn * 64 + j * 16 + l15];
#pragma unroll
  for (int i = 0; i < 4; ++i) {
#pragma unroll
    for (int r = 0; r < 4; ++r) {
      int row = mb + i * 16 + lg * 4 + r;
      if (row < M) {
#pragma unroll
        for (int j = 0; j < 4; ++j) {
          int col = wn * 64 + j * 16 + l15;
          XY[(size_t)row * 256 + col] = f2bf(acc[i][j][r] + bv4[j]);
        }
      }
    }
  }
}

// ---- MFMA GEMM (used for P): C = A(rows via idx, stride LDA)@BT^T + bias --
template <int K, int LDA, int LDC, bool AF32, bool OUTBF16>
__global__ __launch_bounds__(256) void k_mm(
    const void* __restrict__ Ap, const short* __restrict__ BT,
    const float* __restrict__ bias, const int* __restrict__ idx,
    void* __restrict__ Cp, int M) {
  __shared__ short As[128 * 64];
  __shared__ short Bs[128 * 64];
  const int tid = threadIdx.x;
  const int mb = blockIdx.x * 128;
  const int col0 = blockIdx.y * 128;
  const int wave = tid >> 6, lane = tid & 63;
  const int wr = wave >> 1, wc = wave & 1;
  const int l15 = lane & 15, lg = lane >> 4;

  size_t abase[4];
#pragma unroll
  for (int s = 0; s < 4; ++s) {
    int row = (tid + s * 256) >> 3;
    int grow = mb + row;
    int gr = 0;
    if (grow < M) gr = idx ? idx[grow] : grow;
    abase[s] = (size_t)gr * LDA;
  }

  f32x4 acc[4][4];
#pragma unroll
  for (int i = 0; i < 4; ++i)
#pragma unroll
    for (int j = 0; j < 4; ++j) acc[i][j] = (f32x4){0.f, 0.f, 0.f, 0.f};

  for (int k0 = 0; k0 < K; k0 += 64) {
#pragma unroll
    for (int s = 0; s < 4; ++s) {
      int q = tid + s * 256;
      int row = q >> 3, c = q & 7;
      short8 av;
      if (AF32) {
        const float* ap = (const float*)Ap + abase[s] + k0 + c * 8;
        float4 f0 = *(const float4*)ap;
        float4 f1 = *(const float4*)(ap + 4);
        av[0] = f2bf(f0.x); av[1] = f2bf(f0.y);
        av[2] = f2bf(f0.z); av[3] = f2bf(f0.w);
        av[4] = f2bf(f1.x); av[5] = f2bf(f1.y);
        av[6] = f2bf(f1.z); av[7] = f2bf(f1.w);
      } else {
        av = *(const short8*)((const short*)Ap + abase[s] + k0 + c * 8);
      }
      *(short8*)(As + row * 64 + 8 * (c ^ (row & 7))) = av;
      short8 bv = *(const short8*)(BT + (size_t)(col0 + row) * K + k0 + c * 8);
      *(short8*)(Bs + row * 64 + 8 * (c ^ (row & 7))) = bv;
    }
    __syncthreads();
#pragma unroll
    for (int ks = 0; ks < 2; ++ks) {
      int c = ks * 4 + lg;
      short8 af[4], bfv[4];
#pragma unroll
      for (int i = 0; i < 4; ++i) {
        int r = wr * 64 + i * 16 + l15;
        af[i] = *(short8*)(As + r * 64 + 8 * (c ^ (r & 7)));
        int n = wc * 64 + i * 16 + l15;
        bfv[i] = *(short8*)(Bs + n * 64 + 8 * (c ^ (n & 7)));
      }
#pragma unroll
      for (int i = 0; i < 4; ++i)
#pragma unroll
        for (int j = 0; j < 4; ++j)
          acc[i][j] = __builtin_amdgcn_mfma_f32_16x16x32_bf16(
              af[i], bfv[j], acc[i][j], 0, 0, 0);
    }
    __syncthreads();
  }

  float bv4[4];
#pragma unroll
  for (int j = 0; j < 4; ++j) {
    int col = wc * 64 + j * 16 + l15;
    bv4[j] = bias ? bias[col0 + col] : 0.f;
  }
#pragma unroll
  for (int i = 0; i < 4; ++i) {
#pragma unroll
    for (int r = 0; r < 4; ++r) {
      int row = mb + wr * 64 + i * 16 + lg * 4 + r;
      if (row < M) {
#pragma unroll
        for (int j = 0; j < 4; ++j) {
          int col = wc * 64 + j * 16 + l15;
          float v = acc[i][j][r] + bv4[j];
          if (OUTBF16)
            ((short*)Cp)[(size_t)row * LDC + col0 + col] = f2bf(v);
          else
            ((float*)Cp)[(size_t)row * LDC + col0 + col] = v;
        }
      }
    }
  }
}

// ---- fused attention v4: one wave == one center, batched round-trips ----
__global__ __launch_bounds__(256) void k_attn4(
    const short* __restrict__ XY, const float* __restrict__ P,
    const int* __restrict__ nodes, const int* __restrict__ nidx,
    const int* __restrict__ nmask, const short* __restrict__ w2T,
    const float* __restrict__ b2, const float* __restrict__ w3,
    const float* __restrict__ b3, float* __restrict__ out) {
  __shared__ int ni_s[4][32];
  __shared__ float sc_s[4][32];
  __shared__ float att_s[4][32];
  const int tid = threadIdx.x;
  const int wave = tid >> 6, lane = tid & 63;
  const int b = blockIdx.x * 4 + wave;      // this wave's center
  const int l15 = lane & 15, lg = lane >> 4;

  if (lane < 32) ni_s[wave][lane] = nidx[b * DD + lane];

  // ---- round-trip 2: issue EVERYTHING whose address depends only on nidx
  const int m = nmask[(size_t)b * DD + (lane & 31)];     // mask (early)
  const int nid0 = ni_s[wave][l15];
  const int nid1 = ni_s[wave][16 + l15];
  const short* yr0 = XY + (size_t)nid0 * 256 + 128;      // Y half
  const short* yr1 = XY + (size_t)nid1 * 256 + 128;
  short8 y0v[4], y1v[4];
#pragma unroll
  for (int ks = 0; ks < 4; ++ks) {
    const int k0 = ks * 32 + lg * 8;
    y0v[ks] = *(const short8*)(yr0 + k0);
    y1v[ks] = *(const short8*)(yr1 + k0);
  }
  unsigned xv[32];                                        // X prefetch
#pragma unroll
  for (int d = 0; d < 32; ++d)
    xv[d] = *(const unsigned*)(XY + (size_t)ni_s[wave][d] * 256 + 2 * lane);

  const float* pr = P + (size_t)b * EE;

  f32x4 acc[2][8];
#pragma unroll
  for (int i = 0; i < 2; ++i)
#pragma unroll
    for (int j = 0; j < 8; ++j) acc[i][j] = (f32x4){0.f, 0.f, 0.f, 0.f};

#pragma unroll
  for (int ks = 0; ks < 4; ++ks) {
    const int k0 = ks * 32 + lg * 8;
    float4 pa = *(const float4*)(pr + k0);
    float4 pb = *(const float4*)(pr + k0 + 4);
    float pf[8] = {pa.x, pa.y, pa.z, pa.w, pb.x, pb.y, pb.z, pb.w};
    short8 a0, a1;
#pragma unroll
    for (int e = 0; e < 8; ++e) {
      a0[e] = f2bf(fmaxf(bf2f(y0v[ks][e]) + pf[e], 0.f));
      a1[e] = f2bf(fmaxf(bf2f(y1v[ks][e]) + pf[e], 0.f));
    }
    short8 bfv[8];
#pragma unroll
    for (int j = 0; j < 8; ++j)
      bfv[j] = *(const short8*)(w2T + (size_t)(j * 16 + l15) * EE + k0);
    __builtin_amdgcn_s_setprio(1);
#pragma unroll
    for (int j = 0; j < 8; ++j) {
      acc[0][j] = __builtin_amdgcn_mfma_f32_16x16x32_bf16(a0, bfv[j],
                                                          acc[0][j], 0, 0, 0);
      acc[1][j] = __builtin_amdgcn_mfma_f32_16x16x32_bf16(a1, bfv[j],
                                                          acc[1][j], 0, 0, 0);
    }
    __builtin_amdgcn_s_setprio(0);
  }

  // scores: s[row] = sum_col relu(h2[row][col]+b2[col]) * w3[col]
  float b2v[8], w3v[8];
#pragma unroll
  for (int j = 0; j < 8; ++j) {
    int col = j * 16 + l15;
    b2v[j] = b2[col];
    w3v[j] = w3[col];
  }
  float part[2][4];
#pragma unroll
  for (int i = 0; i < 2; ++i)
#pragma unroll
    for (int r = 0; r < 4; ++r) {
      float s = 0.f;
#pragma unroll
      for (int j = 0; j < 8; ++j)
        s += fmaxf(acc[i][j][r] + b2v[j], 0.f) * w3v[j];
      part[i][r] = s;
    }
#pragma unroll
  for (int off = 1; off <= 8; off <<= 1) {
#pragma unroll
    for (int i = 0; i < 2; ++i)
#pragma unroll
      for (int r = 0; r < 4; ++r) part[i][r] += __shfl_xor(part[i][r], off);
  }
  if (l15 == 0) {
#pragma unroll
    for (int i = 0; i < 2; ++i)
#pragma unroll
      for (int r = 0; r < 4; ++r)
        sc_s[wave][i * 16 + lg * 4 + r] = part[i][r];
  }

  // softmax over 32 rows (duplicated in both 32-lane halves)
  const int row = lane & 31;
  float s = sc_s[wave][row] + b3[0];
  if (!m) s = -1e30f;
  float mx = s;
#pragma unroll
  for (int off = 1; off <= 16; off <<= 1) mx = fmaxf(mx, __shfl_xor(mx, off));
  float e = expf(s - mx);
  float sum = e;
#pragma unroll
  for (int off = 1; off <= 16; off <<= 1) sum += __shfl_xor(sum, off);
  if (lane < 32) att_s[wave][row] = e / sum;
  const bool has = (__ballot(m != 0) != 0ull);

  // agg on prefetched X
  float a0 = 0.f, a1 = 0.f;
  if (has) {
#pragma unroll
    for (int d = 0; d < 32; ++d) {
      float a = att_s[wave][d];
      a0 += a * bf2f((short)(xv[d] & 0xffffu));
      a1 += a * bf2f((short)(xv[d] >> 16));
    }
  } else {
    const short* xr = XY + (size_t)nodes[b] * 256;
    unsigned x2 = *(const unsigned*)(xr + 2 * lane);
    a0 = bf2f((short)(x2 & 0xffffu));
    a1 = bf2f((short)(x2 >> 16));
  }
  *(float2*)(out + (size_t)b * EE + 2 * lane) = make_float2(a0, a1);
}

extern "C" void kernel_launch(void* const* d_in, const int* in_sizes, int n_in,
                              void* d_out, int out_size, void* d_ws,
                              size_t ws_size, hipStream_t stream) {
  const int* nodes = (const int*)d_in[0];
  const int* nidx = (const int*)d_in[1];
  const int* nmask = (const int*)d_in[2];
  const float* feature = (const float*)d_in[3];
  const float* W = (const float*)d_in[4];
  const float* bb = (const float*)d_in[5];
  const float* qz = (const float*)d_in[6];
  const float* a1w = (const float*)d_in[7];
  const float* a1b = (const float*)d_in[8];
  const float* a2w = (const float*)d_in[9];
  const float* a2b = (const float*)d_in[10];
  const float* a3w = (const float*)d_in[11];
  const float* a3b = (const float*)d_in[12];
  float* out = (float*)d_out;

  char* ws = (char*)d_ws;
  short* BT2   = (short*)(ws);                       // 128 KiB [256][256] bf16
  float* Wef32 = (float*)(ws + 131072);              // 128 KiB
  short* a1wTc = (short*)(ws + 262144);              // 32 KiB
  short* w2T   = (short*)(ws + 294912);              // 32 KiB
  float* bias2 = (float*)(ws + 327680);              // 1 KiB
  short* XYb   = (short*)(ws + 524288);              // 51.2 MB bf16 [N][256]
  float* Pv    = (float*)(ws + 524288 + 51200000);   // 5.12 MB fp32

  k_prep<<<257, 256, 0, stream>>>(W, qz, a1w, a2w, bb, Wef32, BT2, a1wTc, w2T,
                                  bias2);
  k_compose<<<128, 256, 0, stream>>>(Wef32, a1w, a1b, bb, BT2, bias2);
  // XY = feature @ [We|Wy] + bias2    [100000,256]x[256,256] -> bf16
  k_xy<<<(NN + 63) / 64, 256, 0, stream>>>(feature, BT2, bias2, XYb, NN);
  // P = X[nodes] @ att1_w[128:]       [10000,128]x[128,128] -> fp32
  k_mm<128, 256, 128, false, false><<<dim3((BB_ + 127) / 128, 1), 256, 0,
                                      stream>>>(XYb, a1wTc, nullptr, nodes, Pv,
                                                BB_);
  // fused attention + aggregation (1 wave per center, batched gathers)
  k_attn4<<<BB_ / 4, 256, 0, stream>>>(XYb, Pv, nodes, nidx, nmask, w2T, a2b,
                                       a3w, a3b, out);
}

// Round 9
// 117.946 us; speedup vs baseline: 1.4668x; 1.1862x over previous
//
#include <hip/hip_runtime.h>
#include <hip/hip_bf16.h>
#include <math.h>

#define NN 100000
#define FF 256
#define EE 128
#define BB_ 10000
#define DD 32

typedef __attribute__((ext_vector_type(8))) short short8;
typedef __attribute__((ext_vector_type(4))) float f32x4;

__device__ __forceinline__ short f2bf(float f) {
  __hip_bfloat16 h = __float2bfloat16(f);   // HW RNE cvt
  union { __hip_bfloat16 h; short s; } u; u.h = h;
  return u.s;
}
__device__ __forceinline__ float bf2f(short s) {
  union { unsigned u; float f; } v;
  v.u = ((unsigned)(unsigned short)s) << 16;
  return v.f;
}

// async global->LDS, 16B per lane; LDS dest = wave-uniform base + lane*16
__device__ __forceinline__ void gll16(const float* g, float* lds) {
  __builtin_amdgcn_global_load_lds(
      (const __attribute__((address_space(1))) unsigned int*)g,
      (__attribute__((address_space(3))) unsigned int*)lds, 16, 0, 0);
}

// ---- prep: Wef32 = W*z (fp32), BT2 X-rows, a1wTc, w2T, bias2[0:128] ----
__global__ __launch_bounds__(256) void k_prep(
    const float* __restrict__ W, const float* __restrict__ qz,
    const float* __restrict__ a1w, const float* __restrict__ a2w,
    const float* __restrict__ bb,
    float* __restrict__ Wef32, short* __restrict__ BT2,
    short* __restrict__ a1wTc, short* __restrict__ w2T,
    float* __restrict__ bias2) {
  int i = blockIdx.x * 256 + threadIdx.x;
  if (i < 32768) {                       // (f,e): We = W*z
    int f = i >> 7, e = i & 127;
    float g = qz[f];
    float s = 1.0f / (1.0f + expf(-g));
    float z = fminf(fmaxf(s * 1.2f - 0.1f, 0.0f), 1.0f);
    float v = W[f * 128 + e] * z;
    Wef32[f * 128 + e] = v;
    BT2[e * 256 + f] = f2bf(v);          // X-part rows of combined BT
  } else if (i < 49152) {                // a1wTc[n][k] = a1w[128+k][n]
    int t = i - 32768; int n = t >> 7, k = t & 127;
    a1wTc[n * 128 + k] = f2bf(a1w[(128 + k) * 128 + n]);
  } else if (i < 65536) {                // w2T[n][k] = a2w[k][n]
    int t = i - 49152; int n = t >> 7, k = t & 127;
    w2T[n * 128 + k] = f2bf(a2w[k * 128 + n]);
  } else if (i < 65664) {                // bias2[0:128] = b
    bias2[i - 65536] = bb[i - 65536];
  }
}

// ---- compose: BT2 Y-rows = (We @ A1n)^T, bias2[128:] = b@A1n + a1b ----
__global__ __launch_bounds__(256) void k_compose(
    const float* __restrict__ Wef32, const float* __restrict__ a1w,
    const float* __restrict__ a1b, const float* __restrict__ bb,
    short* __restrict__ BT2, float* __restrict__ bias2) {
  const int n = blockIdx.x;       // 0..127 output col of Y
  const int f = threadIdx.x;      // 0..255
  float s = 0.f;
  for (int e = 0; e < 128; ++e)
    s = fmaf(a1w[e * 128 + n], Wef32[f * 128 + e], s);
  BT2[(size_t)(128 + n) * 256 + f] = f2bf(s);
  if (f == 0) {
    float by = a1b[n];
    for (int e = 0; e < 128; ++e) by = fmaf(bb[e], a1w[e * 128 + n], by);
    bias2[128 + n] = by;
  }
}

// ---- XY GEMM v6: persistent blocks, double-buffered gll staging, counted
// vmcnt (stage loads stay in flight across barriers; never drain to 0 in
// steady state).  XY[M][256] = feature[M][256] @ BT2[256][256]^T + bias2
// 32-row tiles, 3125 tiles, 512 persistent blocks, 4 waves (wave = col blk).
// LDS chunk c of row r holds GLOBAL chunk (c ^ (r&7)); reads XOR the same.
__global__ __launch_bounds__(256) void k_xy(
    const float* __restrict__ feat, const short* __restrict__ BT2,
    const float* __restrict__ bias2, short* __restrict__ XY, int M) {
  __shared__ float As[2][32 * 256];   // 2 x 32 KiB fp32
  const int tid = threadIdx.x;
  const int wave = tid >> 6, lane = tid & 63;
  const int wn = wave;                        // col block
  const int l15 = lane & 15, lg = lane >> 4;
  const int NT = M >> 5;                      // 3125 (M % 32 == 0)
  const int G = gridDim.x;

  // ---- B fragments + bias: hoisted, one L2 round-trip
  short8 bfr[8][4];
#pragma unroll
  for (int ks = 0; ks < 8; ++ks)
#pragma unroll
    for (int j = 0; j < 4; ++j)
      bfr[ks][j] = *(const short8*)(BT2 +
          (size_t)(wn * 64 + j * 16 + l15) * 256 + (ks * 4 + lg) * 8);
  float bv4[4];
#pragma unroll
  for (int j = 0; j < 4; ++j) bv4[j] = bias2[wn * 64 + j * 16 + l15];

  int t = blockIdx.x;
  if (t < NT) {                               // prologue: stage tile t -> buf0
#pragma unroll
    for (int it = 0; it < 8; ++it) {
      int r = it * 4 + wave;
      gll16(feat + (size_t)(t * 32 + r) * 256 + ((lane ^ (r & 7)) * 4),
            &As[0][r * 256]);
    }
  }

  int cur = 0;
  for (; t < NT; t += G) {
    const int tn = t + G;
    __builtin_amdgcn_s_barrier();             // b1: buf (cur^1) free to fill
    if (tn < NT) {
#pragma unroll
      for (int it = 0; it < 8; ++it) {
        int r = it * 4 + wave;
        gll16(feat + (size_t)(tn * 32 + r) * 256 + ((lane ^ (r & 7)) * 4),
              &As[cur ^ 1][r * 256]);
      }
      asm volatile("s_waitcnt vmcnt(8)" ::: "memory");  // cur landed; 8 fly on
    } else {
      asm volatile("s_waitcnt vmcnt(0)" ::: "memory");  // tail: drain all
    }
    __builtin_amdgcn_s_barrier();             // b2: cur visible to all waves
    __builtin_amdgcn_sched_barrier(0);

    f32x4 acc[2][4];
#pragma unroll
    for (int i = 0; i < 2; ++i)
#pragma unroll
      for (int j = 0; j < 4; ++j) acc[i][j] = (f32x4){0.f, 0.f, 0.f, 0.f};

    const float* Ab = &As[cur][0];
#pragma unroll
    for (int ks = 0; ks < 8; ++ks) {
      const int kg = ks * 4 + lg;             // 8-float k-group
#pragma unroll
      for (int i = 0; i < 2; ++i) {
        const int r = i * 16 + l15;
        const int sw = r & 7;
        const int c0 = (2 * kg) ^ sw;
        const int c1 = (2 * kg + 1) ^ sw;
        float4 flo = *(const float4*)(Ab + r * 256 + c0 * 4);
        float4 fhi = *(const float4*)(Ab + r * 256 + c1 * 4);
        short8 af;
        af[0] = f2bf(flo.x); af[1] = f2bf(flo.y);
        af[2] = f2bf(flo.z); af[3] = f2bf(flo.w);
        af[4] = f2bf(fhi.x); af[5] = f2bf(fhi.y);
        af[6] = f2bf(fhi.z); af[7] = f2bf(fhi.w);
        __builtin_amdgcn_s_setprio(1);
#pragma unroll
        for (int j = 0; j < 4; ++j)
          acc[i][j] = __builtin_amdgcn_mfma_f32_16x16x32_bf16(
              af, bfr[ks][j], acc[i][j], 0, 0, 0);
        __builtin_amdgcn_s_setprio(0);
      }
    }

#pragma unroll
    for (int i = 0; i < 2; ++i) {
#pragma unroll
      for (int r = 0; r < 4; ++r) {
        int row = t * 32 + i * 16 + lg * 4 + r;
#pragma unroll
        for (int j = 0; j < 4; ++j) {
          int col = wn * 64 + j * 16 + l15;
          XY[(size_t)row * 256 + col] = f2bf(acc[i][j][r] + bv4[j]);
        }
      }
    }
    cur ^= 1;
  }
}

// ---- MFMA GEMM (used for P): C = A(rows via idx, stride LDA)@BT^T + bias --
template <int K, int LDA, int LDC, bool AF32, bool OUTBF16>
__global__ __launch_bounds__(256) void k_mm(
    const void* __restrict__ Ap, const short* __restrict__ BT,
    const float* __restrict__ bias, const int* __restrict__ idx,
    void* __restrict__ Cp, int M) {
  __shared__ short As[128 * 64];
  __shared__ short Bs[128 * 64];
  const int tid = threadIdx.x;
  const int mb = blockIdx.x * 128;
  const int col0 = blockIdx.y * 128;
  const int wave = tid >> 6, lane = tid & 63;
  const int wr = wave >> 1, wc = wave & 1;
  const int l15 = lane & 15, lg = lane >> 4;

  size_t abase[4];
#pragma unroll
  for (int s = 0; s < 4; ++s) {
    int row = (tid + s * 256) >> 3;
    int grow = mb + row;
    int gr = 0;
    if (grow < M) gr = idx ? idx[grow] : grow;
    abase[s] = (size_t)gr * LDA;
  }

  f32x4 acc[4][4];
#pragma unroll
  for (int i = 0; i < 4; ++i)
#pragma unroll
    for (int j = 0; j < 4; ++j) acc[i][j] = (f32x4){0.f, 0.f, 0.f, 0.f};

  for (int k0 = 0; k0 < K; k0 += 64) {
#pragma unroll
    for (int s = 0; s < 4; ++s) {
      int q = tid + s * 256;
      int row = q >> 3, c = q & 7;
      short8 av;
      if (AF32) {
        const float* ap = (const float*)Ap + abase[s] + k0 + c * 8;
        float4 f0 = *(const float4*)ap;
        float4 f1 = *(const float4*)(ap + 4);
        av[0] = f2bf(f0.x); av[1] = f2bf(f0.y);
        av[2] = f2bf(f0.z); av[3] = f2bf(f0.w);
        av[4] = f2bf(f1.x); av[5] = f2bf(f1.y);
        av[6] = f2bf(f1.z); av[7] = f2bf(f1.w);
      } else {
        av = *(const short8*)((const short*)Ap + abase[s] + k0 + c * 8);
      }
      *(short8*)(As + row * 64 + 8 * (c ^ (row & 7))) = av;
      short8 bv = *(const short8*)(BT + (size_t)(col0 + row) * K + k0 + c * 8);
      *(short8*)(Bs + row * 64 + 8 * (c ^ (row & 7))) = bv;
    }
    __syncthreads();
#pragma unroll
    for (int ks = 0; ks < 2; ++ks) {
      int c = ks * 4 + lg;
      short8 af[4], bfv[4];
#pragma unroll
      for (int i = 0; i < 4; ++i) {
        int r = wr * 64 + i * 16 + l15;
        af[i] = *(short8*)(As + r * 64 + 8 * (c ^ (r & 7)));
        int n = wc * 64 + i * 16 + l15;
        bfv[i] = *(short8*)(Bs + n * 64 + 8 * (c ^ (n & 7)));
      }
#pragma unroll
      for (int i = 0; i < 4; ++i)
#pragma unroll
        for (int j = 0; j < 4; ++j)
          acc[i][j] = __builtin_amdgcn_mfma_f32_16x16x32_bf16(
              af[i], bfv[j], acc[i][j], 0, 0, 0);
    }
    __syncthreads();
  }

  float bv4[4];
#pragma unroll
  for (int j = 0; j < 4; ++j) {
    int col = wc * 64 + j * 16 + l15;
    bv4[j] = bias ? bias[col0 + col] : 0.f;
  }
#pragma unroll
  for (int i = 0; i < 4; ++i) {
#pragma unroll
    for (int r = 0; r < 4; ++r) {
      int row = mb + wr * 64 + i * 16 + lg * 4 + r;
      if (row < M) {
#pragma unroll
        for (int j = 0; j < 4; ++j) {
          int col = wc * 64 + j * 16 + l15;
          float v = acc[i][j][r] + bv4[j];
          if (OUTBF16)
            ((short*)Cp)[(size_t)row * LDC + col0 + col] = f2bf(v);
          else
            ((float*)Cp)[(size_t)row * LDC + col0 + col] = v;
        }
      }
    }
  }
}

// ---- fused attention v4: one wave == one center, batched round-trips ----
__global__ __launch_bounds__(256) void k_attn4(
    const short* __restrict__ XY, const float* __restrict__ P,
    const int* __restrict__ nodes, const int* __restrict__ nidx,
    const int* __restrict__ nmask, const short* __restrict__ w2T,
    const float* __restrict__ b2, const float* __restrict__ w3,
    const float* __restrict__ b3, float* __restrict__ out) {
  __shared__ int ni_s[4][32];
  __shared__ float sc_s[4][32];
  __shared__ float att_s[4][32];
  const int tid = threadIdx.x;
  const int wave = tid >> 6, lane = tid & 63;
  const int b = blockIdx.x * 4 + wave;      // this wave's center
  const int l15 = lane & 15, lg = lane >> 4;

  if (lane < 32) ni_s[wave][lane] = nidx[b * DD + lane];

  // ---- round-trip 2: issue EVERYTHING whose address depends only on nidx
  const int m = nmask[(size_t)b * DD + (lane & 31)];     // mask (early)
  const int nid0 = ni_s[wave][l15];
  const int nid1 = ni_s[wave][16 + l15];
  const short* yr0 = XY + (size_t)nid0 * 256 + 128;      // Y half
  const short* yr1 = XY + (size_t)nid1 * 256 + 128;
  short8 y0v[4], y1v[4];
#pragma unroll
  for (int ks = 0; ks < 4; ++ks) {
    const int k0 = ks * 32 + lg * 8;
    y0v[ks] = *(const short8*)(yr0 + k0);
    y1v[ks] = *(const short8*)(yr1 + k0);
  }
  unsigned xv[32];                                        // X prefetch
#pragma unroll
  for (int d = 0; d < 32; ++d)
    xv[d] = *(const unsigned*)(XY + (size_t)ni_s[wave][d] * 256 + 2 * lane);

  const float* pr = P + (size_t)b * EE;

  f32x4 acc[2][8];
#pragma unroll
  for (int i = 0; i < 2; ++i)
#pragma unroll
    for (int j = 0; j < 8; ++j) acc[i][j] = (f32x4){0.f, 0.f, 0.f, 0.f};

#pragma unroll
  for (int ks = 0; ks < 4; ++ks) {
    const int k0 = ks * 32 + lg * 8;
    float4 pa = *(const float4*)(pr + k0);
    float4 pb = *(const float4*)(pr + k0 + 4);
    float pf[8] = {pa.x, pa.y, pa.z, pa.w, pb.x, pb.y, pb.z, pb.w};
    short8 a0, a1;
#pragma unroll
    for (int e = 0; e < 8; ++e) {
      a0[e] = f2bf(fmaxf(bf2f(y0v[ks][e]) + pf[e], 0.f));
      a1[e] = f2bf(fmaxf(bf2f(y1v[ks][e]) + pf[e], 0.f));
    }
    short8 bfv[8];
#pragma unroll
    for (int j = 0; j < 8; ++j)
      bfv[j] = *(const short8*)(w2T + (size_t)(j * 16 + l15) * EE + k0);
    __builtin_amdgcn_s_setprio(1);
#pragma unroll
    for (int j = 0; j < 8; ++j) {
      acc[0][j] = __builtin_amdgcn_mfma_f32_16x16x32_bf16(a0, bfv[j],
                                                          acc[0][j], 0, 0, 0);
      acc[1][j] = __builtin_amdgcn_mfma_f32_16x16x32_bf16(a1, bfv[j],
                                                          acc[1][j], 0, 0, 0);
    }
    __builtin_amdgcn_s_setprio(0);
  }

  // scores: s[row] = sum_col relu(h2[row][col]+b2[col]) * w3[col]
  float b2v[8], w3v[8];
#pragma unroll
  for (int j = 0; j < 8; ++j) {
    int col = j * 16 + l15;
    b2v[j] = b2[col];
    w3v[j] = w3[col];
  }
  float part[2][4];
#pragma unroll
  for (int i = 0; i < 2; ++i)
#pragma unroll
    for (int r = 0; r < 4; ++r) {
      float s = 0.f;
#pragma unroll
      for (int j = 0; j < 8; ++j)
        s += fmaxf(acc[i][j][r] + b2v[j], 0.f) * w3v[j];
      part[i][r] = s;
    }
#pragma unroll
  for (int off = 1; off <= 8; off <<= 1) {
#pragma unroll
    for (int i = 0; i < 2; ++i)
#pragma unroll
      for (int r = 0; r < 4; ++r) part[i][r] += __shfl_xor(part[i][r], off);
  }
  if (l15 == 0) {
#pragma unroll
    for (int i = 0; i < 2; ++i)
#pragma unroll
      for (int r = 0; r < 4; ++r)
        sc_s[wave][i * 16 + lg * 4 + r] = part[i][r];
  }

  // softmax over 32 rows (duplicated in both 32-lane halves)
  const int row = lane & 31;
  float s = sc_s[wave][row] + b3[0];
  if (!m) s = -1e30f;
  float mx = s;
#pragma unroll
  for (int off = 1; off <= 16; off <<= 1) mx = fmaxf(mx, __shfl_xor(mx, off));
  float e = expf(s - mx);
  float sum = e;
#pragma unroll
  for (int off = 1; off <= 16; off <<= 1) sum += __shfl_xor(sum, off);
  if (lane < 32) att_s[wave][row] = e / sum;
  const bool has = (__ballot(m != 0) != 0ull);

  // agg on prefetched X
  float a0 = 0.f, a1 = 0.f;
  if (has) {
#pragma unroll
    for (int d = 0; d < 32; ++d) {
      float a = att_s[wave][d];
      a0 += a * bf2f((short)(xv[d] & 0xffffu));
      a1 += a * bf2f((short)(xv[d] >> 16));
    }
  } else {
    const short* xr = XY + (size_t)nodes[b] * 256;
    unsigned x2 = *(const unsigned*)(xr + 2 * lane);
    a0 = bf2f((short)(x2 & 0xffffu));
    a1 = bf2f((short)(x2 >> 16));
  }
  *(float2*)(out + (size_t)b * EE + 2 * lane) = make_float2(a0, a1);
}

extern "C" void kernel_launch(void* const* d_in, const int* in_sizes, int n_in,
                              void* d_out, int out_size, void* d_ws,
                              size_t ws_size, hipStream_t stream) {
  const int* nodes = (const int*)d_in[0];
  const int* nidx = (const int*)d_in[1];
  const int* nmask = (const int*)d_in[2];
  const float* feature = (const float*)d_in[3];
  const float* W = (const float*)d_in[4];
  const float* bb = (const float*)d_in[5];
  const float* qz = (const float*)d_in[6];
  const float* a1w = (const float*)d_in[7];
  const float* a1b = (const float*)d_in[8];
  const float* a2w = (const float*)d_in[9];
  const float* a2b = (const float*)d_in[10];
  const float* a3w = (const float*)d_in[11];
  const float* a3b = (const float*)d_in[12];
  float* out = (float*)d_out;

  char* ws = (char*)d_ws;
  short* BT2   = (short*)(ws);                       // 128 KiB [256][256] bf16
  float* Wef32 = (float*)(ws + 131072);              // 128 KiB
  short* a1wTc = (short*)(ws + 262144);              // 32 KiB
  short* w2T   = (short*)(ws + 294912);              // 32 KiB
  float* bias2 = (float*)(ws + 327680);              // 1 KiB
  short* XYb   = (short*)(ws + 524288);              // 51.2 MB bf16 [N][256]
  float* Pv    = (float*)(ws + 524288 + 51200000);   // 5.12 MB fp32

  k_prep<<<257, 256, 0, stream>>>(W, qz, a1w, a2w, bb, Wef32, BT2, a1wTc, w2T,
                                  bias2);
  k_compose<<<128, 256, 0, stream>>>(Wef32, a1w, a1b, bb, BT2, bias2);
  // XY = feature @ [We|Wy] + bias2    [100000,256]x[256,256] -> bf16
  k_xy<<<512, 256, 0, stream>>>(feature, BT2, bias2, XYb, NN);
  // P = X[nodes] @ att1_w[128:]       [10000,128]x[128,128] -> fp32
  k_mm<128, 256, 128, false, false><<<dim3((BB_ + 127) / 128, 1), 256, 0,
                                      stream>>>(XYb, a1wTc, nullptr, nodes, Pv,
                                                BB_);
  // fused attention + aggregation (1 wave per center, batched gathers)
  k_attn4<<<BB_ / 4, 256, 0, stream>>>(XYb, Pv, nodes, nidx, nmask, w2T, a2b,
                                       a3w, a3b, out);
}